// Round 8
// baseline (626.799 us; speedup 1.0000x reference)
//
#include <hip/hip_runtime.h>
#include <hip/hip_bf16.h>

// Problem constants
#define DIM    16
#define BATCH  32
#define KL     4
#define NTS    512
#define NC     4
#define NPAR   16
#define DTF    (1.0f/512.0f)
#define BST    40     // bf16 operand row stride (ushort): 16B-aligned frags, 2-way banks = free
#define FST    20     // f32 tile row stride

using short8 = __attribute__((ext_vector_type(8))) short;
using f32x4  = __attribute__((ext_vector_type(4))) float;

__device__ __forceinline__ float b2f(__hip_bfloat16 x) { return __bfloat162float(x); }

__device__ __forceinline__ float ldval(const void* p, int idx, bool isf32) {
  return isf32 ? ((const float*)p)[idx]
               : __bfloat162float(((const __hip_bfloat16*)p)[idx]);
}

__device__ __forceinline__ unsigned short f2bf(float x) {   // f32->bf16 RNE
  unsigned u = __float_as_uint(x);
  unsigned r = u + 0x7FFFu + ((u >> 16) & 1u);
  return (unsigned short)(r >> 16);
}
__device__ __forceinline__ float bf2f(unsigned short h) {
  return __uint_as_float(((unsigned)h) << 16);
}
__device__ __forceinline__ short8 ldfrag(const unsigned short* p) {
  return *(const short8*)p;
}
__device__ __forceinline__ short8 negbf8(short8 a) {
  union { short8 s; unsigned u[4]; } v; v.s = a;
  #pragma unroll
  for (int q = 0; q < 4; ++q) v.u[q] ^= 0x80008000u;
  return v.s;
}
// split-precision MFMA: C += (Ah+Al)*(Bh+Bl) minus Al*Bl (~2^-18)
__device__ __forceinline__ f32x4 mm3(short8 Ah, short8 Al, short8 Bh, short8 Bl, f32x4 acc) {
  acc = __builtin_amdgcn_mfma_f32_16x16x32_bf16(Ah, Bh, acc, 0, 0, 0);
  acc = __builtin_amdgcn_mfma_f32_16x16x32_bf16(Al, Bh, acc, 0, 0, 0);
  acc = __builtin_amdgcn_mfma_f32_16x16x32_bf16(Ah, Bl, acc, 0, 0, 0);
  return acc;
}

__global__ __launch_bounds__(256, 1)
void lindblad_evolve(const void* __restrict__ g_params,
                     const void* __restrict__ g_H0re, const void* __restrict__ g_H0im,
                     const void* __restrict__ g_Hcre, const void* __restrict__ g_Hcim,
                     const void* __restrict__ g_Lre,  const void* __restrict__ g_Lim,
                     const void* __restrict__ g_r0re, const void* __restrict__ g_r0im,
                     float* __restrict__ g_out)
{
  __shared__ __align__(16) unsigned short sGh[2][16*BST], sGl[2][16*BST]; // G'(t), double-buffered
  __shared__ __align__(16) unsigned short sPh[16*BST], sPl[16*BST];       // rho^T' = [rr^T|ri^T]
  __shared__ __align__(16) unsigned short sTh[KL][16*BST], sTl[KL][16*BST];
  __shared__ __align__(16) unsigned short sLh[KL][16*BST], sLl[KL][16*BST];
  __shared__ __align__(16) float sMr[16*FST], sMi[16*FST];                // M = G*rho
  __shared__ float sU[NTS][NC];
  __shared__ int sFlag;

  const int tid = threadIdx.x;
  const int b   = blockIdx.x;
  const int i   = tid >> 4;
  const int j   = tid & 15;
  const int wv  = tid >> 6;
  const int ln  = tid & 63;
  const int fm  = ln & 15;
  const int fq  = ln >> 4;
  const int row0 = fq * 4;                        // C-layout: row = row0+reg, col = fm
  const int fOff  = fm*BST + fq*8;
  const int fOffS = fm*BST + ((fq*8 + 16) & 31);

  // ---- input storage-dtype detection (R1/R2-verified) ----
  if (tid == 0) sFlag = 0;
  __syncthreads();
  {
    float v = b2f(((const __hip_bfloat16*)g_H0re)[tid]);
    if (!(fabsf(v) <= 1e10f)) atomicOr(&sFlag, 1);
  }
  __syncthreads();
  const bool isf32 = (sFlag != 0);

  // ---- B-spline control pulses (R4-verified) ----
  {
    float kn[20];
    kn[0] = 0.f; kn[1] = 0.f; kn[2] = 0.f;
    #pragma unroll
    for (int q = 0; q < 14; ++q) kn[3 + q] = (float)q / 13.0f;
    kn[17] = 1.f; kn[18] = 1.f; kn[19] = 1.f;
    #pragma unroll
    for (int rep = 0; rep < 2; ++rep) {
      const int ts = tid + rep * 256;
      const float t = (float)ts * DTF;
      float B[19];
      #pragma unroll
      for (int q = 0; q < 19; ++q) B[q] = (kn[q] <= t && t < kn[q+1]) ? 1.f : 0.f;
      #pragma unroll
      for (int d = 1; d <= 3; ++d) {
        #pragma unroll
        for (int q = 0; q + d < 19; ++q) {
          float ld = kn[q+d]   - kn[q];
          float rd = kn[q+d+1] - kn[q+1];
          float lv = (ld > 0.f) ? (t - kn[q])     / ld * B[q]   : 0.f;
          float rv = (rd > 0.f) ? (kn[q+d+1] - t) / rd * B[q+1] : 0.f;
          B[q] = lv + rv;
        }
      }
      #pragma unroll
      for (int c = 0; c < NC; ++c) {
        float s = 0.f;
        #pragma unroll
        for (int q = 0; q < NPAR; ++q) s += B[q] * ldval(g_params, q*NC + c, isf32);
        sU[ts][c] = s;
      }
    }
  }

  // ---- constants: G0/Gc per (i,j) thread (regs), L' staged hi/lo (R7-verified) ----
  float g0r, g0i, gcr[NC], gci[NC];
  {
    const int ij = i*16 + j, ji = j*16 + i;
    float h0r = 0.5f * (ldval(g_H0re, ij, isf32) + ldval(g_H0re, ji, isf32));
    float h0i = 0.5f * (ldval(g_H0im, ij, isf32) - ldval(g_H0im, ji, isf32));
    float ldr = 0.f, ldi = 0.f;
    for (int k = 0; k < KL; ++k) {
      #pragma unroll
      for (int m = 0; m < DIM; ++m) {
        float ar = ldval(g_Lre, k*256 + m*16 + i, isf32), ai = ldval(g_Lim, k*256 + m*16 + i, isf32);
        float br = ldval(g_Lre, k*256 + m*16 + j, isf32), bi = ldval(g_Lim, k*256 + m*16 + j, isf32);
        ldr += ar*br + ai*bi;
        ldi += ar*bi - ai*br;
      }
    }
    g0r =  h0i - 0.5f*ldr;
    g0i = -h0r - 0.5f*ldi;
    #pragma unroll
    for (int c = 0; c < NC; ++c) {
      float hr = 0.5f * (ldval(g_Hcre, c*256 + ij, isf32) + ldval(g_Hcre, c*256 + ji, isf32));
      float hi = 0.5f * (ldval(g_Hcim, c*256 + ij, isf32) - ldval(g_Hcim, c*256 + ji, isf32));
      gcr[c] =  hi;
      gci[c] = -hr;
    }
    #pragma unroll
    for (int k = 0; k < KL; ++k) {
      float lr = ldval(g_Lre, k*256 + ij, isf32);
      float li = ldval(g_Lim, k*256 + ij, isf32);
      unsigned short h;
      h = f2bf(lr); sLh[k][i*BST + j]      = h; sLl[k][i*BST + j]      = f2bf(lr - bf2f(h));
      h = f2bf(li); sLh[k][i*BST + 16 + j] = h; sLl[k][i*BST + 16 + j] = f2bf(li - bf2f(h));
    }
  }

  // ---- init sP(0), sG[0] (per (i,j) thread) ----
  {
    float r0 = ldval(g_r0re, b*256 + i*16 + j, isf32);
    float m0 = ldval(g_r0im, b*256 + i*16 + j, isf32);
    unsigned short h;
    h = f2bf(r0); sPh[j*BST + i]      = h; sPl[j*BST + i]      = f2bf(r0 - bf2f(h));
    h = f2bf(m0); sPh[j*BST + 16 + i] = h; sPl[j*BST + 16 + i] = f2bf(m0 - bf2f(h));
    float u0 = sU[0][0], u1 = sU[0][1], u2 = sU[0][2], u3 = sU[0][3];
    float gr = g0r + u0*gcr[0] + u1*gcr[1] + u2*gcr[2] + u3*gcr[3];
    float gi = g0i + u0*gci[0] + u1*gci[1] + u2*gci[2] + u3*gci[3];
    h = f2bf(gr); sGh[0][i*BST + j]      = h; sGl[0][i*BST + j]      = f2bf(gr - bf2f(h));
    h = f2bf(gi); sGh[0][i*BST + 16 + j] = h; sGl[0][i*BST + 16 + j] = f2bf(gi - bf2f(h));
  }

  __syncthreads();   // sU, sL staged (also covers sP/sG init; re-synced by B1 anyway)

  // ---- preload loop-constant fragments (R7-verified mappings) ----
  short8 A0h, A0l, A1h, A1l;       // phase-1 A operands (wave's L'_k)
  short8 JBh[KL], JBl[KL];         // phase-2 B operands (w0: Jr straight; w1: Ji swap+neg)
  if (wv == 0) {
    A0h = ldfrag(&sLh[0][fOff]); A0l = ldfrag(&sLl[0][fOff]);   // T0r
    #pragma unroll
    for (int k = 0; k < KL; ++k) { JBh[k] = ldfrag(&sLh[k][fOff]); JBl[k] = ldfrag(&sLl[k][fOff]); }
  } else if (wv == 1) {
    A0h = ldfrag(&sLh[0][fOff]); A0l = ldfrag(&sLl[0][fOff]);   // T0i
    A1h = ldfrag(&sLh[1][fOff]); A1l = ldfrag(&sLl[1][fOff]);   // T1r/T1i
    #pragma unroll
    for (int k = 0; k < KL; ++k) {
      short8 h = ldfrag(&sLh[k][fOffS]);
      short8 l = ldfrag(&sLl[k][fOffS]);
      if (fq < 2) { h = negbf8(h); l = negbf8(l); }
      JBh[k] = h; JBl[k] = l;
    }
  } else if (wv == 2) {
    A0h = ldfrag(&sLh[2][fOff]); A0l = ldfrag(&sLl[2][fOff]);
  } else {
    A0h = ldfrag(&sLh[3][fOff]); A0l = ldfrag(&sLl[3][fOff]);
  }

  // ---- rho master in C-layout registers: w0 = re, w1 = im ----
  float rm[4] = {0.f, 0.f, 0.f, 0.f};
  if (wv == 0) {
    #pragma unroll
    for (int q = 0; q < 4; ++q) rm[q] = ldval(g_r0re, b*256 + (row0+q)*16 + fm, isf32);
  } else if (wv == 1) {
    #pragma unroll
    for (int q = 0; q < 4; ++q) rm[q] = ldval(g_r0im, b*256 + (row0+q)*16 + fm, isf32);
  }

  #define WRITE_TILE_F32(dst, acc)                                   \
    { _Pragma("unroll") for (int r_ = 0; r_ < 4; ++r_)               \
        (dst)[(row0 + r_)*FST + fm] = (acc)[r_]; }
  #define WRITE_TILE_BF(dh, dl, acc, co)                             \
    { _Pragma("unroll") for (int r_ = 0; r_ < 4; ++r_) {             \
        float v_ = (acc)[r_];                                        \
        unsigned short h_ = f2bf(v_);                                \
        (dh)[(row0 + r_)*BST + (co) + fm] = h_;                      \
        (dl)[(row0 + r_)*BST + (co) + fm] = f2bf(v_ - bf2f(h_)); } }

  // ---- main Euler loop (2 barriers/step) ----
  #pragma unroll 1
  for (int t = 0; t < NTS; ++t) {
    __syncthreads();   // B1: sP(t), sG[t&1] visible
    const int cur = t & 1, nxt = cur ^ 1;

    // ---- phase 1: M = G*rho, T_k = L_k*rho; stage G'(t+1) ----
    {
      short8 Brh = ldfrag(&sPh[fOff]),  Brl = ldfrag(&sPl[fOff]);
      if (fq >= 2) { Brh = negbf8(Brh); Brl = negbf8(Brl); }
      short8 Bih = ldfrag(&sPh[fOffS]), Bil = ldfrag(&sPl[fOffS]);

      if (wv == 0) {
        short8 Gh = ldfrag(&sGh[cur][fOff]), Gl = ldfrag(&sGl[cur][fOff]);
        f32x4 aMr = {0.f,0.f,0.f,0.f}, aMi = {0.f,0.f,0.f,0.f}, aT = {0.f,0.f,0.f,0.f};
        aMr = mm3(Gh, Gl, Brh, Brl, aMr);
        aMi = mm3(Gh, Gl, Bih, Bil, aMi);
        aT  = mm3(A0h, A0l, Brh, Brl, aT);           // T0r
        WRITE_TILE_F32(sMr, aMr);
        WRITE_TILE_F32(sMi, aMi);
        WRITE_TILE_BF(sTh[0], sTl[0], aT, 0);
      } else if (wv == 1) {
        f32x4 a0 = {0.f,0.f,0.f,0.f}, a1 = {0.f,0.f,0.f,0.f}, a2 = {0.f,0.f,0.f,0.f};
        a0 = mm3(A0h, A0l, Bih, Bil, a0);            // T0i
        a1 = mm3(A1h, A1l, Brh, Brl, a1);            // T1r
        a2 = mm3(A1h, A1l, Bih, Bil, a2);            // T1i
        WRITE_TILE_BF(sTh[0], sTl[0], a0, 16);
        WRITE_TILE_BF(sTh[1], sTl[1], a1, 0);
        WRITE_TILE_BF(sTh[1], sTl[1], a2, 16);
      } else if (wv == 2) {
        f32x4 a1 = {0.f,0.f,0.f,0.f}, a2 = {0.f,0.f,0.f,0.f};
        a1 = mm3(A0h, A0l, Brh, Brl, a1);            // T2r
        a2 = mm3(A0h, A0l, Bih, Bil, a2);            // T2i
        WRITE_TILE_BF(sTh[2], sTl[2], a1, 0);
        WRITE_TILE_BF(sTh[2], sTl[2], a2, 16);
      } else {
        f32x4 a1 = {0.f,0.f,0.f,0.f}, a2 = {0.f,0.f,0.f,0.f};
        a1 = mm3(A0h, A0l, Brh, Brl, a1);            // T3r
        a2 = mm3(A0h, A0l, Bih, Bil, a2);            // T3i
        WRITE_TILE_BF(sTh[3], sTl[3], a1, 0);
        WRITE_TILE_BF(sTh[3], sTl[3], a2, 16);
      }

      // stage G'(t+1) into the other buffer (per (i,j) thread; no reader until next B1)
      const int tn = (t + 1 < NTS) ? (t + 1) : t;
      float u0 = sU[tn][0], u1 = sU[tn][1], u2 = sU[tn][2], u3 = sU[tn][3];
      float gr = g0r + u0*gcr[0] + u1*gcr[1] + u2*gcr[2] + u3*gcr[3];
      float gi = g0i + u0*gci[0] + u1*gci[1] + u2*gci[2] + u3*gci[3];
      unsigned short h;
      h = f2bf(gr); sGh[nxt][i*BST + j]      = h; sGl[nxt][i*BST + j]      = f2bf(gr - bf2f(h));
      h = f2bf(gi); sGh[nxt][i*BST + 16 + j] = h; sGl[nxt][i*BST + 16 + j] = f2bf(gi - bf2f(h));
    }

    __syncthreads();   // B2: sT, sM visible

    // ---- phase 2': J in-register; update rho master; restage sP; store pops ----
    if (wv == 0) {          // re half: rr += dt*(Mr + Mr^T + Jr)
      f32x4 a01 = {0.f,0.f,0.f,0.f}, a23 = {0.f,0.f,0.f,0.f};
      a01 = mm3(ldfrag(&sTh[0][fOff]), ldfrag(&sTl[0][fOff]), JBh[0], JBl[0], a01);
      a23 = mm3(ldfrag(&sTh[2][fOff]), ldfrag(&sTl[2][fOff]), JBh[2], JBl[2], a23);
      a01 = mm3(ldfrag(&sTh[1][fOff]), ldfrag(&sTl[1][fOff]), JBh[1], JBl[1], a01);
      a23 = mm3(ldfrag(&sTh[3][fOff]), ldfrag(&sTl[3][fOff]), JBh[3], JBl[3], a23);
      #pragma unroll
      for (int q = 0; q < 4; ++q) {
        float mr  = sMr[(row0+q)*FST + fm];
        float mrt = sMr[fm*FST + row0 + q];
        rm[q] += DTF * (mr + mrt + (a01[q] + a23[q]));
        unsigned short h = f2bf(rm[q]);
        sPh[fm*BST + row0 + q] = h;
        sPl[fm*BST + row0 + q] = f2bf(rm[q] - bf2f(h));
      }
      if ((unsigned)(fm - row0) < 4u)
        g_out[(t*BATCH + b)*DIM + fm] = rm[fm - row0];
    } else if (wv == 1) {   // im half: ri += dt*(Mi - Mi^T + Ji)
      f32x4 a01 = {0.f,0.f,0.f,0.f}, a23 = {0.f,0.f,0.f,0.f};
      a01 = mm3(ldfrag(&sTh[0][fOff]), ldfrag(&sTl[0][fOff]), JBh[0], JBl[0], a01);
      a23 = mm3(ldfrag(&sTh[2][fOff]), ldfrag(&sTl[2][fOff]), JBh[2], JBl[2], a23);
      a01 = mm3(ldfrag(&sTh[1][fOff]), ldfrag(&sTl[1][fOff]), JBh[1], JBl[1], a01);
      a23 = mm3(ldfrag(&sTh[3][fOff]), ldfrag(&sTl[3][fOff]), JBh[3], JBl[3], a23);
      #pragma unroll
      for (int q = 0; q < 4; ++q) {
        float mi  = sMi[(row0+q)*FST + fm];
        float mit = sMi[fm*FST + row0 + q];
        rm[q] += DTF * (mi - mit + (a01[q] + a23[q]));
        unsigned short h = f2bf(rm[q]);
        sPh[fm*BST + 16 + row0 + q] = h;
        sPl[fm*BST + 16 + row0 + q] = f2bf(rm[q] - bf2f(h));
      }
    }
    // waves 2-3: nothing until B1
  }
}

extern "C" void kernel_launch(void* const* d_in, const int* in_sizes, int n_in,
                              void* d_out, int out_size, void* d_ws, size_t ws_size,
                              hipStream_t stream) {
  (void)out_size; (void)d_ws; (void)ws_size;
  const void *P, *H0r, *H0i, *Hcr, *Hci, *Lr, *Li, *R0r, *R0i;
  int idx64 = -1;
  for (int q = 0; q < n_in; ++q) if (in_sizes[q] == 64) idx64 = q;
  if (idx64 == 6) {   // alphabetical fallback
    H0i = d_in[0]; H0r = d_in[1];
    Hci = d_in[2]; Hcr = d_in[3];
    Li  = d_in[4]; Lr  = d_in[5];
    P   = d_in[6];
    R0i = d_in[7]; R0r = d_in[8];
  } else {            // documented setup_inputs() dict order (R4-verified)
    P   = d_in[0];
    H0r = d_in[1]; H0i = d_in[2];
    Hcr = d_in[3]; Hci = d_in[4];
    Lr  = d_in[5]; Li  = d_in[6];
    R0r = d_in[7]; R0i = d_in[8];
  }
  lindblad_evolve<<<dim3(BATCH), dim3(256), 0, stream>>>(
      P, H0r, H0i, Hcr, Hci, Lr, Li, R0r, R0i, (float*)d_out);
}

// Round 9
// 610.089 us; speedup vs baseline: 1.0274x; 1.0274x over previous
//
#include <hip/hip_runtime.h>
#include <hip/hip_bf16.h>

#define DIM    16
#define BATCH  32
#define KL     4
#define NTS    512
#define NC     4
#define NPAR   16
#define DTF    (1.0f/512.0f)
#define BST    40     // bf16 operand row stride (ushort)
#define FST    20     // f32 tile row stride

using short8 = __attribute__((ext_vector_type(8))) short;
using f32x4  = __attribute__((ext_vector_type(4))) float;

__device__ __forceinline__ float b2f(__hip_bfloat16 x) { return __bfloat162float(x); }

__device__ __forceinline__ float ldval(const void* p, int idx, bool isf32) {
  return isf32 ? ((const float*)p)[idx]
               : __bfloat162float(((const __hip_bfloat16*)p)[idx]);
}
__device__ __forceinline__ unsigned short f2bf(float x) {   // f32->bf16 RNE
  unsigned u = __float_as_uint(x);
  unsigned r = u + 0x7FFFu + ((u >> 16) & 1u);
  return (unsigned short)(r >> 16);
}
__device__ __forceinline__ float bf2f(unsigned short h) {
  return __uint_as_float(((unsigned)h) << 16);
}
__device__ __forceinline__ short8 ldfrag(const unsigned short* p) {
  return *(const short8*)p;
}
__device__ __forceinline__ short8 negbf8(short8 a) {
  union { short8 s; unsigned u[4]; } v; v.s = a;
  #pragma unroll
  for (int q = 0; q < 4; ++q) v.u[q] ^= 0x80008000u;
  return v.s;
}
__device__ __forceinline__ f32x4 mm3(short8 Ah, short8 Al, short8 Bh, short8 Bl, f32x4 acc) {
  acc = __builtin_amdgcn_mfma_f32_16x16x32_bf16(Ah, Bh, acc, 0, 0, 0);
  acc = __builtin_amdgcn_mfma_f32_16x16x32_bf16(Al, Bh, acc, 0, 0, 0);
  acc = __builtin_amdgcn_mfma_f32_16x16x32_bf16(Ah, Bl, acc, 0, 0, 0);
  return acc;
}
__device__ __forceinline__ void packfrag(const float* v, short8& hi, short8& lo) {
  union { short8 s; unsigned short e[8]; } H, L;
  #pragma unroll
  for (int q = 0; q < 8; ++q) {
    unsigned short h = f2bf(v[q]);
    H.e[q] = h;
    L.e[q] = f2bf(v[q] - bf2f(h));
  }
  hi = H.s; lo = L.s;
}

__global__ __launch_bounds__(256, 1)
void lindblad_evolve(const void* __restrict__ g_params,
                     const void* __restrict__ g_H0re, const void* __restrict__ g_H0im,
                     const void* __restrict__ g_Hcre, const void* __restrict__ g_Hcim,
                     const void* __restrict__ g_Lre,  const void* __restrict__ g_Lim,
                     const void* __restrict__ g_r0re, const void* __restrict__ g_r0im,
                     float* __restrict__ g_out)
{
  __shared__ __align__(16) unsigned short sPh[16*BST], sPl[16*BST];         // rho^T' hi/lo
  __shared__ __align__(16) unsigned short sTh[KL][16*BST], sTl[KL][16*BST]; // T'_k
  __shared__ __align__(16) unsigned short sLh[KL][16*BST], sLl[KL][16*BST]; // L'_k
  __shared__ __align__(16) float sMr[16*FST], sMi[16*FST];                  // M = G*rho
  __shared__ __align__(16) float sU[NTS][NC];                               // pulses (16B rows)
  __shared__ __align__(16) float sPops[NTS*DIM];   // pops buffer; first 2560 f32 reused as G-scratch at setup
  __shared__ int sFlag;

  const int tid = threadIdx.x;
  const int b   = blockIdx.x;
  const int i   = tid >> 4;
  const int j   = tid & 15;
  const int wv  = tid >> 6;
  const int ln  = tid & 63;
  const int fm  = ln & 15;
  const int fq  = ln >> 4;
  const int row0 = fq * 4;                       // C-layout: row = row0+reg, col = fm
  const int fOff  = fm*BST + fq*8;
  const int fOffS = fm*BST + ((fq*8 + 16) & 31);

  // ---- input storage-dtype detection (R1/R2-verified) ----
  if (tid == 0) sFlag = 0;
  __syncthreads();
  {
    float v = b2f(((const __hip_bfloat16*)g_H0re)[tid]);
    if (!(fabsf(v) <= 1e10f)) atomicOr(&sFlag, 1);
  }
  __syncthreads();
  const bool isf32 = (sFlag != 0);

  // ---- B-spline control pulses (R4-verified) ----
  {
    float kn[20];
    kn[0] = 0.f; kn[1] = 0.f; kn[2] = 0.f;
    #pragma unroll
    for (int q = 0; q < 14; ++q) kn[3 + q] = (float)q / 13.0f;
    kn[17] = 1.f; kn[18] = 1.f; kn[19] = 1.f;
    #pragma unroll
    for (int rep = 0; rep < 2; ++rep) {
      const int ts = tid + rep * 256;
      const float t = (float)ts * DTF;
      float B[19];
      #pragma unroll
      for (int q = 0; q < 19; ++q) B[q] = (kn[q] <= t && t < kn[q+1]) ? 1.f : 0.f;
      #pragma unroll
      for (int d = 1; d <= 3; ++d) {
        #pragma unroll
        for (int q = 0; q + d < 19; ++q) {
          float ld = kn[q+d]   - kn[q];
          float rd = kn[q+d+1] - kn[q+1];
          float lv = (ld > 0.f) ? (t - kn[q])     / ld * B[q]   : 0.f;
          float rv = (rd > 0.f) ? (kn[q+d+1] - t) / rd * B[q+1] : 0.f;
          B[q] = lv + rv;
        }
      }
      #pragma unroll
      for (int c = 0; c < NC; ++c) {
        float s = 0.f;
        #pragma unroll
        for (int q = 0; q < NPAR; ++q) s += B[q] * ldval(g_params, q*NC + c, isf32);
        sU[ts][c] = s;
      }
    }
  }

  // ---- constants: per-thread G0/Gc element -> LDS scratch (in sPops); L' staged hi/lo ----
  {
    float* scr = sPops;   // scratch planes: 0=G0r 1=G0i 2+2c=Gc_cr 3+2c=Gc_ci (10 x 256 f32)
    const int ij = i*16 + j, ji = j*16 + i;
    float h0r = 0.5f * (ldval(g_H0re, ij, isf32) + ldval(g_H0re, ji, isf32));
    float h0i = 0.5f * (ldval(g_H0im, ij, isf32) - ldval(g_H0im, ji, isf32));
    float ldr = 0.f, ldi = 0.f;
    for (int k = 0; k < KL; ++k) {
      #pragma unroll
      for (int m = 0; m < DIM; ++m) {
        float ar = ldval(g_Lre, k*256 + m*16 + i, isf32), ai = ldval(g_Lim, k*256 + m*16 + i, isf32);
        float br = ldval(g_Lre, k*256 + m*16 + j, isf32), bi = ldval(g_Lim, k*256 + m*16 + j, isf32);
        ldr += ar*br + ai*bi;
        ldi += ar*bi - ai*br;
      }
    }
    scr[0*256 + ij] =  h0i - 0.5f*ldr;   // G0r
    scr[1*256 + ij] = -h0r - 0.5f*ldi;   // G0i
    #pragma unroll
    for (int c = 0; c < NC; ++c) {
      float hr = 0.5f * (ldval(g_Hcre, c*256 + ij, isf32) + ldval(g_Hcre, c*256 + ji, isf32));
      float hi = 0.5f * (ldval(g_Hcim, c*256 + ij, isf32) - ldval(g_Hcim, c*256 + ji, isf32));
      scr[(2 + 2*c)*256 + ij] =  hi;     // Gc_r = -i*herm(Hc) (re)
      scr[(3 + 2*c)*256 + ij] = -hr;     // Gc_i
    }
    #pragma unroll
    for (int k = 0; k < KL; ++k) {
      float lr = ldval(g_Lre, k*256 + ij, isf32);
      float li = ldval(g_Lim, k*256 + ij, isf32);
      unsigned short h;
      h = f2bf(lr); sLh[k][i*BST + j]      = h; sLl[k][i*BST + j]      = f2bf(lr - bf2f(h));
      h = f2bf(li); sLh[k][i*BST + 16 + j] = h; sLl[k][i*BST + 16 + j] = f2bf(li - bf2f(h));
    }
    // init rho^T'(0)
    float r0 = ldval(g_r0re, b*256 + ij, isf32);
    float m0 = ldval(g_r0im, b*256 + ij, isf32);
    unsigned short h;
    h = f2bf(r0); sPh[j*BST + i]      = h; sPl[j*BST + i]      = f2bf(r0 - bf2f(h));
    h = f2bf(m0); sPh[j*BST + 16 + i] = h; sPl[j*BST + 16 + i] = f2bf(m0 - bf2f(h));
  }

  __syncthreads();   // scratch, sL, sP, sU visible

  // ---- preload loop-constant fragments (R7-verified mappings) ----
  short8 A0h, A0l, A1h, A1l;       // phase-1 A operands (wave's L'_k)
  short8 JBh[KL], JBl[KL];         // phase-2 B operands (w0: Jr straight; w1: Ji swap+neg)
  float  G0v[8], Gcv[NC][8];       // w0 only: G fragment values in f32
  short8 Ghc, Glc;                 // w0 only: current G'(t) fragment (bf16 hi/lo)
  if (wv == 0) {
    A0h = ldfrag(&sLh[0][fOff]); A0l = ldfrag(&sLl[0][fOff]);   // T0r
    #pragma unroll
    for (int k = 0; k < KL; ++k) { JBh[k] = ldfrag(&sLh[k][fOff]); JBl[k] = ldfrag(&sLl[k][fOff]); }
    // G fragment constants: A-layout lane (fq,fm) covers k = fq*8..fq*8+7;
    // k<16 -> re plane, k>=16 -> im plane; column base = (fq&1)*8
    const int comp = (fq < 2) ? 0 : 1;
    const int base = (fq & 1) * 8;
    const float* scr = sPops;
    {
      const float* s0 = &scr[comp*256 + fm*16 + base];
      float4 va = *(const float4*)s0, vb = *(const float4*)(s0 + 4);
      G0v[0]=va.x; G0v[1]=va.y; G0v[2]=va.z; G0v[3]=va.w;
      G0v[4]=vb.x; G0v[5]=vb.y; G0v[6]=vb.z; G0v[7]=vb.w;
    }
    #pragma unroll
    for (int c = 0; c < NC; ++c) {
      const float* s0 = &scr[(2 + 2*c + comp)*256 + fm*16 + base];
      float4 va = *(const float4*)s0, vb = *(const float4*)(s0 + 4);
      Gcv[c][0]=va.x; Gcv[c][1]=va.y; Gcv[c][2]=va.z; Gcv[c][3]=va.w;
      Gcv[c][4]=vb.x; Gcv[c][5]=vb.y; Gcv[c][6]=vb.z; Gcv[c][7]=vb.w;
    }
    // G'(0)
    float4 uv = *(const float4*)&sU[0][0];
    float gv[8];
    #pragma unroll
    for (int q = 0; q < 8; ++q)
      gv[q] = G0v[q] + uv.x*Gcv[0][q] + uv.y*Gcv[1][q] + uv.z*Gcv[2][q] + uv.w*Gcv[3][q];
    packfrag(gv, Ghc, Glc);
  } else if (wv == 1) {
    A0h = ldfrag(&sLh[0][fOff]); A0l = ldfrag(&sLl[0][fOff]);   // T0i
    A1h = ldfrag(&sLh[1][fOff]); A1l = ldfrag(&sLl[1][fOff]);   // T1r/T1i
    #pragma unroll
    for (int k = 0; k < KL; ++k) {
      short8 h = ldfrag(&sLh[k][fOffS]);
      short8 l = ldfrag(&sLl[k][fOffS]);
      if (fq < 2) { h = negbf8(h); l = negbf8(l); }
      JBh[k] = h; JBl[k] = l;
    }
  } else if (wv == 2) {
    A0h = ldfrag(&sLh[2][fOff]); A0l = ldfrag(&sLl[2][fOff]);
  } else {
    A0h = ldfrag(&sLh[3][fOff]); A0l = ldfrag(&sLl[3][fOff]);
  }

  // ---- rho master in C-layout registers: w0 = re, w1 = im ----
  float rm[4] = {0.f, 0.f, 0.f, 0.f};
  if (wv == 0) {
    #pragma unroll
    for (int q = 0; q < 4; ++q) rm[q] = ldval(g_r0re, b*256 + (row0+q)*16 + fm, isf32);
  } else if (wv == 1) {
    #pragma unroll
    for (int q = 0; q < 4; ++q) rm[q] = ldval(g_r0im, b*256 + (row0+q)*16 + fm, isf32);
  }

  #define WRITE_TILE_F32(dst, acc)                                   \
    { _Pragma("unroll") for (int r_ = 0; r_ < 4; ++r_)               \
        (dst)[(row0 + r_)*FST + fm] = (acc)[r_]; }
  #define WRITE_TILE_BF(dh, dl, acc, co)                             \
    { _Pragma("unroll") for (int r_ = 0; r_ < 4; ++r_) {             \
        float v_ = (acc)[r_];                                        \
        unsigned short h_ = f2bf(v_);                                \
        (dh)[(row0 + r_)*BST + (co) + fm] = h_;                      \
        (dl)[(row0 + r_)*BST + (co) + fm] = f2bf(v_ - bf2f(h_)); } }

  // ---- main Euler loop (2 barriers/step, NO global memory ops inside) ----
  #pragma unroll 1
  for (int t = 0; t < NTS; ++t) {
    __syncthreads();   // B1: sP(t) visible

    // ---- phase 1: M = G*rho, T_k = L_k*rho ----
    {
      short8 Brh = ldfrag(&sPh[fOff]),  Brl = ldfrag(&sPl[fOff]);
      if (fq >= 2) { Brh = negbf8(Brh); Brl = negbf8(Brl); }
      short8 Bih = ldfrag(&sPh[fOffS]), Bil = ldfrag(&sPl[fOffS]);

      if (wv == 0) {
        f32x4 aMr = {0.f,0.f,0.f,0.f}, aMi = {0.f,0.f,0.f,0.f}, aT = {0.f,0.f,0.f,0.f};
        aMr = mm3(Ghc, Glc, Brh, Brl, aMr);
        aMi = mm3(Ghc, Glc, Bih, Bil, aMi);
        aT  = mm3(A0h, A0l, Brh, Brl, aT);           // T0r
        WRITE_TILE_F32(sMr, aMr);
        WRITE_TILE_F32(sMi, aMi);
        WRITE_TILE_BF(sTh[0], sTl[0], aT, 0);
        // rebuild G'(t+1) in registers (no LDS consumers)
        const int tn = (t + 1 < NTS) ? (t + 1) : t;
        float4 uv = *(const float4*)&sU[tn][0];
        float gv[8];
        #pragma unroll
        for (int q = 0; q < 8; ++q)
          gv[q] = G0v[q] + uv.x*Gcv[0][q] + uv.y*Gcv[1][q] + uv.z*Gcv[2][q] + uv.w*Gcv[3][q];
        packfrag(gv, Ghc, Glc);
      } else if (wv == 1) {
        f32x4 a0 = {0.f,0.f,0.f,0.f}, a1 = {0.f,0.f,0.f,0.f}, a2 = {0.f,0.f,0.f,0.f};
        a0 = mm3(A0h, A0l, Bih, Bil, a0);            // T0i
        a1 = mm3(A1h, A1l, Brh, Brl, a1);            // T1r
        a2 = mm3(A1h, A1l, Bih, Bil, a2);            // T1i
        WRITE_TILE_BF(sTh[0], sTl[0], a0, 16);
        WRITE_TILE_BF(sTh[1], sTl[1], a1, 0);
        WRITE_TILE_BF(sTh[1], sTl[1], a2, 16);
      } else if (wv == 2) {
        f32x4 a1 = {0.f,0.f,0.f,0.f}, a2 = {0.f,0.f,0.f,0.f};
        a1 = mm3(A0h, A0l, Brh, Brl, a1);            // T2r
        a2 = mm3(A0h, A0l, Bih, Bil, a2);            // T2i
        WRITE_TILE_BF(sTh[2], sTl[2], a1, 0);
        WRITE_TILE_BF(sTh[2], sTl[2], a2, 16);
      } else {
        f32x4 a1 = {0.f,0.f,0.f,0.f}, a2 = {0.f,0.f,0.f,0.f};
        a1 = mm3(A0h, A0l, Brh, Brl, a1);            // T3r
        a2 = mm3(A0h, A0l, Bih, Bil, a2);            // T3i
        WRITE_TILE_BF(sTh[3], sTl[3], a1, 0);
        WRITE_TILE_BF(sTh[3], sTl[3], a2, 16);
      }
    }

    __syncthreads();   // B2: sT, sM visible

    // ---- phase 2: J in-register (ILP-4); update rho master; restage sP; pops -> LDS ----
    if (wv == 0) {          // re half: rr += dt*(Mr + Mr^T + Jr)
      f32x4 a0 = {0.f,0.f,0.f,0.f}, a1 = {0.f,0.f,0.f,0.f},
            a2 = {0.f,0.f,0.f,0.f}, a3 = {0.f,0.f,0.f,0.f};
      a0 = mm3(ldfrag(&sTh[0][fOff]), ldfrag(&sTl[0][fOff]), JBh[0], JBl[0], a0);
      a1 = mm3(ldfrag(&sTh[1][fOff]), ldfrag(&sTl[1][fOff]), JBh[1], JBl[1], a1);
      a2 = mm3(ldfrag(&sTh[2][fOff]), ldfrag(&sTl[2][fOff]), JBh[2], JBl[2], a2);
      a3 = mm3(ldfrag(&sTh[3][fOff]), ldfrag(&sTl[3][fOff]), JBh[3], JBl[3], a3);
      float4 mt = *(const float4*)&sMr[fm*FST + row0];   // transposed Mr (contiguous)
      float mtv[4] = {mt.x, mt.y, mt.z, mt.w};
      #pragma unroll
      for (int q = 0; q < 4; ++q) {
        float mr = sMr[(row0+q)*FST + fm];
        rm[q] += DTF * (mr + mtv[q] + ((a0[q] + a1[q]) + (a2[q] + a3[q])));
        unsigned short h = f2bf(rm[q]);
        sPh[fm*BST + row0 + q] = h;
        sPl[fm*BST + row0 + q] = f2bf(rm[q] - bf2f(h));
        if (fm == row0 + q) sPops[t*DIM + fm] = rm[q];   // diagonal -> pops buffer
      }
    } else if (wv == 1) {   // im half: ri += dt*(Mi - Mi^T + Ji)
      f32x4 a0 = {0.f,0.f,0.f,0.f}, a1 = {0.f,0.f,0.f,0.f},
            a2 = {0.f,0.f,0.f,0.f}, a3 = {0.f,0.f,0.f,0.f};
      a0 = mm3(ldfrag(&sTh[0][fOff]), ldfrag(&sTl[0][fOff]), JBh[0], JBl[0], a0);
      a1 = mm3(ldfrag(&sTh[1][fOff]), ldfrag(&sTl[1][fOff]), JBh[1], JBl[1], a1);
      a2 = mm3(ldfrag(&sTh[2][fOff]), ldfrag(&sTl[2][fOff]), JBh[2], JBl[2], a2);
      a3 = mm3(ldfrag(&sTh[3][fOff]), ldfrag(&sTl[3][fOff]), JBh[3], JBl[3], a3);
      float4 mt = *(const float4*)&sMi[fm*FST + row0];
      float mtv[4] = {mt.x, mt.y, mt.z, mt.w};
      #pragma unroll
      for (int q = 0; q < 4; ++q) {
        float mi = sMi[(row0+q)*FST + fm];
        rm[q] += DTF * (mi - mtv[q] + ((a0[q] + a1[q]) + (a2[q] + a3[q])));
        unsigned short h = f2bf(rm[q]);
        sPh[fm*BST + 16 + row0 + q] = h;
        sPl[fm*BST + 16 + row0 + q] = f2bf(rm[q] - bf2f(h));
      }
    }
    // waves 2-3: idle until B1
  }

  // ---- final coalesced pops flush: 8192 f32 per block ----
  __syncthreads();
  #pragma unroll
  for (int s = 0; s < NTS*DIM/256; ++s) {
    int idx = s*256 + tid;                      // idx = t*16 + d
    g_out[(idx >> 4)*(BATCH*DIM) + b*DIM + (idx & 15)] = sPops[idx];
  }
}

extern "C" void kernel_launch(void* const* d_in, const int* in_sizes, int n_in,
                              void* d_out, int out_size, void* d_ws, size_t ws_size,
                              hipStream_t stream) {
  (void)out_size; (void)d_ws; (void)ws_size;
  const void *P, *H0r, *H0i, *Hcr, *Hci, *Lr, *Li, *R0r, *R0i;
  int idx64 = -1;
  for (int q = 0; q < n_in; ++q) if (in_sizes[q] == 64) idx64 = q;
  if (idx64 == 6) {   // alphabetical fallback
    H0i = d_in[0]; H0r = d_in[1];
    Hci = d_in[2]; Hcr = d_in[3];
    Li  = d_in[4]; Lr  = d_in[5];
    P   = d_in[6];
    R0i = d_in[7]; R0r = d_in[8];
  } else {            // documented setup_inputs() dict order (R4-verified)
    P   = d_in[0];
    H0r = d_in[1]; H0i = d_in[2];
    Hcr = d_in[3]; Hci = d_in[4];
    Lr  = d_in[5]; Li  = d_in[6];
    R0r = d_in[7]; R0i = d_in[8];
  }
  lindblad_evolve<<<dim3(BATCH), dim3(256), 0, stream>>>(
      P, H0r, H0i, Hcr, Hci, Lr, Li, R0r, R0i, (float*)d_out);
}

// Round 10
// 422.079 us; speedup vs baseline: 1.4850x; 1.4454x over previous
//
#include <hip/hip_runtime.h>
#include <hip/hip_bf16.h>

#define DIM    16
#define BATCH  32
#define KL     4
#define NTS    512
#define NC     4
#define NPAR   16
#define DTF    (1.0f/512.0f)
#define BST    40     // bf16 operand row stride (ushort)
#define FST    20     // f32 tile row stride

using short8  = __attribute__((ext_vector_type(8))) short;
using short4v = __attribute__((ext_vector_type(4))) short;
using f32x4   = __attribute__((ext_vector_type(4))) float;

__device__ __forceinline__ float b2f(__hip_bfloat16 x) { return __bfloat162float(x); }

__device__ __forceinline__ float ldval(const void* p, int idx, bool isf32) {
  return isf32 ? ((const float*)p)[idx]
               : __bfloat162float(((const __hip_bfloat16*)p)[idx]);
}
__device__ __forceinline__ unsigned short f2bf(float x) {   // RNE (setup/L only)
  unsigned u = __float_as_uint(x);
  unsigned r = u + 0x7FFFu + ((u >> 16) & 1u);
  return (unsigned short)(r >> 16);
}
__device__ __forceinline__ float bf2f(unsigned short h) {
  return __uint_as_float(((unsigned)h) << 16);
}
// cheap trunc-trunc hi/lo split: pair represents v to ~2^-16 rel (4 VALU)
__device__ __forceinline__ void split2(float v, unsigned short& h, unsigned short& l) {
  unsigned u = __float_as_uint(v);
  h = (unsigned short)(u >> 16);
  float r = v - __uint_as_float(u & 0xFFFF0000u);
  l = (unsigned short)(__float_as_uint(r) >> 16);
}
__device__ __forceinline__ short8 ldfrag(const unsigned short* p) {
  return *(const short8*)p;
}
__device__ __forceinline__ short8 negbf8(short8 a) {
  union { short8 s; unsigned u[4]; } v; v.s = a;
  #pragma unroll
  for (int q = 0; q < 4; ++q) v.u[q] ^= 0x80008000u;
  return v.s;
}
__device__ __forceinline__ f32x4 mm3(short8 Ah, short8 Al, short8 Bh, short8 Bl, f32x4 acc) {
  acc = __builtin_amdgcn_mfma_f32_16x16x32_bf16(Ah, Bh, acc, 0, 0, 0);
  acc = __builtin_amdgcn_mfma_f32_16x16x32_bf16(Al, Bh, acc, 0, 0, 0);
  acc = __builtin_amdgcn_mfma_f32_16x16x32_bf16(Ah, Bl, acc, 0, 0, 0);
  return acc;
}
__device__ __forceinline__ void packfrag(const float* v, short8& hi, short8& lo) {
  union { short8 s; unsigned short e[8]; } H, L;
  #pragma unroll
  for (int q = 0; q < 8; ++q) split2(v[q], H.e[q], L.e[q]);
  hi = H.s; lo = L.s;
}

__global__ __launch_bounds__(512, 1)
void lindblad_evolve(const void* __restrict__ g_params,
                     const void* __restrict__ g_H0re, const void* __restrict__ g_H0im,
                     const void* __restrict__ g_Hcre, const void* __restrict__ g_Hcim,
                     const void* __restrict__ g_Lre,  const void* __restrict__ g_Lim,
                     const void* __restrict__ g_r0re, const void* __restrict__ g_r0im,
                     float* __restrict__ g_out)
{
  __shared__ __align__(16) unsigned short sPh[16*BST], sPl[16*BST];         // rho^T' hi/lo
  __shared__ __align__(16) unsigned short sTh[KL][16*BST], sTl[KL][16*BST]; // T'_k
  __shared__ __align__(16) unsigned short sLh[KL][16*BST], sLl[KL][16*BST]; // L'_k
  __shared__ __align__(16) float sMr[16*FST],  sMi[16*FST];   // M normal layout
  __shared__ __align__(16) float sMrT[16*FST], sMiT[16*FST];  // M transposed layout
  __shared__ __align__(16) float sU[NTS][NC];
  __shared__ __align__(16) float sPops[NTS*DIM];  // pops; first 2560 f32 = setup scratch
  __shared__ int sFlag;

  const int tid = threadIdx.x;
  const int b   = blockIdx.x;
  const int i   = tid >> 4;        // (valid for tid<256 setup staging)
  const int j   = tid & 15;
  const int wv  = tid >> 6;        // wave 0..7
  const int ln  = tid & 63;
  const int fm  = ln & 15;
  const int fq  = ln >> 4;
  const int row0 = fq * 4;
  const int fOff  = fm*BST + fq*8;
  const int fOffS = fm*BST + ((fq*8 + 16) & 31);

  // ---- input storage-dtype detection ----
  if (tid == 0) sFlag = 0;
  __syncthreads();
  if (tid < 256) {
    float v = b2f(((const __hip_bfloat16*)g_H0re)[tid]);
    if (!(fabsf(v) <= 1e10f)) atomicOr(&sFlag, 1);
  }
  __syncthreads();
  const bool isf32 = (sFlag != 0);

  // ---- B-spline control pulses (512 threads: one pass) ----
  {
    float kn[20];
    kn[0] = 0.f; kn[1] = 0.f; kn[2] = 0.f;
    #pragma unroll
    for (int q = 0; q < 14; ++q) kn[3 + q] = (float)q / 13.0f;
    kn[17] = 1.f; kn[18] = 1.f; kn[19] = 1.f;
    const int ts = tid;
    const float t = (float)ts * DTF;
    float B[19];
    #pragma unroll
    for (int q = 0; q < 19; ++q) B[q] = (kn[q] <= t && t < kn[q+1]) ? 1.f : 0.f;
    #pragma unroll
    for (int d = 1; d <= 3; ++d) {
      #pragma unroll
      for (int q = 0; q + d < 19; ++q) {
        float ld = kn[q+d]   - kn[q];
        float rd = kn[q+d+1] - kn[q+1];
        float lv = (ld > 0.f) ? (t - kn[q])     / ld * B[q]   : 0.f;
        float rv = (rd > 0.f) ? (kn[q+d+1] - t) / rd * B[q+1] : 0.f;
        B[q] = lv + rv;
      }
    }
    #pragma unroll
    for (int c = 0; c < NC; ++c) {
      float s = 0.f;
      #pragma unroll
      for (int q = 0; q < NPAR; ++q) s += B[q] * ldval(g_params, q*NC + c, isf32);
      sU[ts][c] = s;
    }
  }

  // ---- constants staging (threads 0..255, elementwise (i,j)) ----
  if (tid < 256) {
    float* scr = sPops;   // planes: 0=G0r 1=G0i 2+2c=Gc_r 3+2c=Gc_i
    const int ij = i*16 + j, ji = j*16 + i;
    float h0r = 0.5f * (ldval(g_H0re, ij, isf32) + ldval(g_H0re, ji, isf32));
    float h0i = 0.5f * (ldval(g_H0im, ij, isf32) - ldval(g_H0im, ji, isf32));
    float ldr = 0.f, ldi = 0.f;
    for (int k = 0; k < KL; ++k) {
      #pragma unroll
      for (int m = 0; m < DIM; ++m) {
        float ar = ldval(g_Lre, k*256 + m*16 + i, isf32), ai = ldval(g_Lim, k*256 + m*16 + i, isf32);
        float br = ldval(g_Lre, k*256 + m*16 + j, isf32), bi = ldval(g_Lim, k*256 + m*16 + j, isf32);
        ldr += ar*br + ai*bi;
        ldi += ar*bi - ai*br;
      }
    }
    scr[0*256 + ij] =  h0i - 0.5f*ldr;   // G0r
    scr[1*256 + ij] = -h0r - 0.5f*ldi;   // G0i
    #pragma unroll
    for (int c = 0; c < NC; ++c) {
      float hr = 0.5f * (ldval(g_Hcre, c*256 + ij, isf32) + ldval(g_Hcre, c*256 + ji, isf32));
      float hi = 0.5f * (ldval(g_Hcim, c*256 + ij, isf32) - ldval(g_Hcim, c*256 + ji, isf32));
      scr[(2 + 2*c)*256 + ij] =  hi;
      scr[(3 + 2*c)*256 + ij] = -hr;
    }
    // L': RNE hi/lo split (constant — error integrates, keep tightest)
    #pragma unroll
    for (int k = 0; k < KL; ++k) {
      float lr = ldval(g_Lre, k*256 + ij, isf32);
      float li = ldval(g_Lim, k*256 + ij, isf32);
      unsigned short h;
      h = f2bf(lr); sLh[k][i*BST + j]      = h; sLl[k][i*BST + j]      = f2bf(lr - bf2f(h));
      h = f2bf(li); sLh[k][i*BST + 16 + j] = h; sLl[k][i*BST + 16 + j] = f2bf(li - bf2f(h));
    }
    // rho^T'(0)
    float r0 = ldval(g_r0re, b*256 + ij, isf32);
    float m0 = ldval(g_r0im, b*256 + ij, isf32);
    unsigned short h, l;
    split2(r0, h, l); sPh[j*BST + i]      = h; sPl[j*BST + i]      = l;
    split2(m0, h, l); sPh[j*BST + 16 + i] = h; sPl[j*BST + 16 + i] = l;
  }

  __syncthreads();   // scratch, sL, sP, sU visible

  // ---- per-wave loop-constant preloads ----
  short8 Ah, Al;                   // wv0/1: G' frag (rebuilt per step); wv2-5: L'_k frag
  short8 JBh[KL], JBl[KL];         // wv6: straight; wv7: swap+neg
  float  G0v[8], Gcv[NC][8];       // wv0/1 only
  float  rm[4] = {0.f,0.f,0.f,0.f};// wv6: rho_re master; wv7: rho_im master

  if (wv < 2) {
    const int comp = (fq < 2) ? 0 : 1;      // k<16 -> re plane, k>=16 -> im plane
    const int base = (fq & 1) * 8;
    const float* scr = sPops;
    {
      const float* s0 = &scr[comp*256 + fm*16 + base];
      f32x4 va = *(const f32x4*)s0, vb = *(const f32x4*)(s0 + 4);
      G0v[0]=va[0]; G0v[1]=va[1]; G0v[2]=va[2]; G0v[3]=va[3];
      G0v[4]=vb[0]; G0v[5]=vb[1]; G0v[6]=vb[2]; G0v[7]=vb[3];
    }
    #pragma unroll
    for (int c = 0; c < NC; ++c) {
      const float* s0 = &scr[(2 + 2*c + comp)*256 + fm*16 + base];
      f32x4 va = *(const f32x4*)s0, vb = *(const f32x4*)(s0 + 4);
      Gcv[c][0]=va[0]; Gcv[c][1]=va[1]; Gcv[c][2]=va[2]; Gcv[c][3]=va[3];
      Gcv[c][4]=vb[0]; Gcv[c][5]=vb[1]; Gcv[c][6]=vb[2]; Gcv[c][7]=vb[3];
    }
    f32x4 uv = *(const f32x4*)&sU[0][0];
    float gv[8];
    #pragma unroll
    for (int q = 0; q < 8; ++q)
      gv[q] = G0v[q] + uv[0]*Gcv[0][q] + uv[1]*Gcv[1][q] + uv[2]*Gcv[2][q] + uv[3]*Gcv[3][q];
    packfrag(gv, Ah, Al);
  } else if (wv < 6) {
    const int k = wv - 2;
    Ah = ldfrag(&sLh[k][fOff]);
    Al = ldfrag(&sLl[k][fOff]);
  } else if (wv == 6) {
    #pragma unroll
    for (int k = 0; k < KL; ++k) { JBh[k] = ldfrag(&sLh[k][fOff]); JBl[k] = ldfrag(&sLl[k][fOff]); }
    #pragma unroll
    for (int q = 0; q < 4; ++q) rm[q] = ldval(g_r0re, b*256 + (row0+q)*16 + fm, isf32);
  } else {
    #pragma unroll
    for (int k = 0; k < KL; ++k) {
      short8 h = ldfrag(&sLh[k][fOffS]);
      short8 l = ldfrag(&sLl[k][fOffS]);
      if (fq < 2) { h = negbf8(h); l = negbf8(l); }
      JBh[k] = h; JBl[k] = l;
    }
    #pragma unroll
    for (int q = 0; q < 4; ++q) rm[q] = ldval(g_r0im, b*256 + (row0+q)*16 + fm, isf32);
  }

  // ---- main Euler loop: 2 barriers/step, specialized waves ----
  #pragma unroll 1
  for (int t = 0; t < NTS; ++t) {
    __syncthreads();   // B1: sP(t) visible

    if (wv < 2) {
      // ---- M half: wv0 -> Mr (Br operand), wv1 -> Mi (Bi operand) ----
      short8 Bh, Bl;
      if (wv == 0) {
        Bh = ldfrag(&sPh[fOff]);  Bl = ldfrag(&sPl[fOff]);
        if (fq >= 2) { Bh = negbf8(Bh); Bl = negbf8(Bl); }
      } else {
        Bh = ldfrag(&sPh[fOffS]); Bl = ldfrag(&sPl[fOffS]);
      }
      f32x4 a = {0.f,0.f,0.f,0.f};
      a = mm3(Ah, Al, Bh, Bl, a);
      float* Mn = (wv == 0) ? sMr  : sMi;
      float* Mt = (wv == 0) ? sMrT : sMiT;
      #pragma unroll
      for (int r = 0; r < 4; ++r) Mn[(row0 + r)*FST + fm] = a[r];   // normal layout
      *(f32x4*)&Mt[fm*FST + row0] = a;                              // transposed layout (b128)
      // rebuild G'(t+1) fragment in registers
      const int tn = (t + 1 < NTS) ? (t + 1) : t;
      f32x4 uv = *(const f32x4*)&sU[tn][0];
      float gv[8];
      #pragma unroll
      for (int q = 0; q < 8; ++q)
        gv[q] = G0v[q] + uv[0]*Gcv[0][q] + uv[1]*Gcv[1][q] + uv[2]*Gcv[2][q] + uv[3]*Gcv[3][q];
      packfrag(gv, Ah, Al);
    } else if (wv < 6) {
      // ---- T_k pair: T_kr and T_ki ----
      const int k = wv - 2;
      short8 Brh = ldfrag(&sPh[fOff]),  Brl = ldfrag(&sPl[fOff]);
      if (fq >= 2) { Brh = negbf8(Brh); Brl = negbf8(Brl); }
      short8 Bih = ldfrag(&sPh[fOffS]), Bil = ldfrag(&sPl[fOffS]);
      f32x4 ar = {0.f,0.f,0.f,0.f}, ai = {0.f,0.f,0.f,0.f};
      ar = mm3(Ah, Al, Brh, Brl, ar);
      ai = mm3(Ah, Al, Bih, Bil, ai);
      #pragma unroll
      for (int r = 0; r < 4; ++r) {
        unsigned short h, l;
        split2(ar[r], h, l);
        sTh[k][(row0 + r)*BST + fm]      = h;
        sTl[k][(row0 + r)*BST + fm]      = l;
        split2(ai[r], h, l);
        sTh[k][(row0 + r)*BST + 16 + fm] = h;
        sTl[k][(row0 + r)*BST + 16 + fm] = l;
      }
    }
    // wv6/7: idle in phase 1

    __syncthreads();   // B2: sT, sM visible

    if (wv >= 6) {
      // ---- J + update: wv6 -> re (Jr), wv7 -> im (Ji) ----
      f32x4 a0 = {0.f,0.f,0.f,0.f}, a1 = {0.f,0.f,0.f,0.f},
            a2 = {0.f,0.f,0.f,0.f}, a3 = {0.f,0.f,0.f,0.f};
      a0 = mm3(ldfrag(&sTh[0][fOff]), ldfrag(&sTl[0][fOff]), JBh[0], JBl[0], a0);
      a1 = mm3(ldfrag(&sTh[1][fOff]), ldfrag(&sTl[1][fOff]), JBh[1], JBl[1], a1);
      a2 = mm3(ldfrag(&sTh[2][fOff]), ldfrag(&sTl[2][fOff]), JBh[2], JBl[2], a2);
      a3 = mm3(ldfrag(&sTh[3][fOff]), ldfrag(&sTl[3][fOff]), JBh[3], JBl[3], a3);
      const float* Mt = (wv == 6) ? sMrT : sMiT;
      const float* Mn = (wv == 6) ? sMr  : sMi;
      f32x4 d1 = *(const f32x4*)&Mt[fm*FST + row0];   // M[row0+q][fm]
      f32x4 d2 = *(const f32x4*)&Mn[fm*FST + row0];   // M[fm][row0+q] (transposed)
      union { short4v s; unsigned short e[4]; } HH, LL;
      if (wv == 6) {
        #pragma unroll
        for (int q = 0; q < 4; ++q) {
          rm[q] += DTF * (d1[q] + d2[q] + ((a0[q] + a1[q]) + (a2[q] + a3[q])));
          split2(rm[q], HH.e[q], LL.e[q]);
        }
        *(short4v*)&sPh[fm*BST + row0] = HH.s;   // b64 writes
        *(short4v*)&sPl[fm*BST + row0] = LL.s;
        if ((unsigned)(fm - row0) < 4u) sPops[t*DIM + fm] = rm[fm - row0];
      } else {
        #pragma unroll
        for (int q = 0; q < 4; ++q) {
          rm[q] += DTF * (d1[q] - d2[q] + ((a0[q] + a1[q]) + (a2[q] + a3[q])));
          split2(rm[q], HH.e[q], LL.e[q]);
        }
        *(short4v*)&sPh[fm*BST + 16 + row0] = HH.s;
        *(short4v*)&sPl[fm*BST + 16 + row0] = LL.s;
      }
    }
  }

  // ---- final coalesced pops flush ----
  __syncthreads();
  #pragma unroll
  for (int s = 0; s < NTS*DIM/512; ++s) {
    int idx = s*512 + tid;                      // idx = t*16 + d
    g_out[(idx >> 4)*(BATCH*DIM) + b*DIM + (idx & 15)] = sPops[idx];
  }
}

extern "C" void kernel_launch(void* const* d_in, const int* in_sizes, int n_in,
                              void* d_out, int out_size, void* d_ws, size_t ws_size,
                              hipStream_t stream) {
  (void)out_size; (void)d_ws; (void)ws_size;
  const void *P, *H0r, *H0i, *Hcr, *Hci, *Lr, *Li, *R0r, *R0i;
  int idx64 = -1;
  for (int q = 0; q < n_in; ++q) if (in_sizes[q] == 64) idx64 = q;
  if (idx64 == 6) {   // alphabetical fallback
    H0i = d_in[0]; H0r = d_in[1];
    Hci = d_in[2]; Hcr = d_in[3];
    Li  = d_in[4]; Lr  = d_in[5];
    P   = d_in[6];
    R0i = d_in[7]; R0r = d_in[8];
  } else {            // documented setup_inputs() dict order (R4-verified)
    P   = d_in[0];
    H0r = d_in[1]; H0i = d_in[2];
    Hcr = d_in[3]; Hci = d_in[4];
    Lr  = d_in[5]; Li  = d_in[6];
    R0r = d_in[7]; R0i = d_in[8];
  }
  lindblad_evolve<<<dim3(BATCH), dim3(512), 0, stream>>>(
      P, H0r, H0i, Hcr, Hci, Lr, Li, R0r, R0i, (float*)d_out);
}